// Round 7
// baseline (397.262 us; speedup 1.0000x reference)
//
#include <hip/hip_runtime.h>

// SAGE_Net: 2-layer GraphSAGE, N=100k, E=1.6M, 128->128->64, fp32.
// R7: row-major bf16 hi/lo everywhere (planes deleted); fused transposed
// MFMA GEMM1+GEMM2 with h tile in LDS (no global round-trip); aggregation
// with vector col loads (no cndmask select) + raw-hi accumulate in layer 1.

typedef unsigned int uint32;
typedef short bf16x4 __attribute__((ext_vector_type(4)));
typedef short bf16x8 __attribute__((ext_vector_type(8)));
typedef float f32x16 __attribute__((ext_vector_type(16)));

__device__ __forceinline__ uint32 pack_bf16_rne(float a, float b) {
    uint32 ua = __float_as_uint(a);
    uint32 ub = __float_as_uint(b);
    uint32 ra = (ua + 0x7fffu + ((ua >> 16) & 1u)) >> 16;
    uint32 rb = (ub + 0x7fffu + ((ub >> 16) & 1u)) >> 16;
    return ra | (rb << 16);
}
__device__ __forceinline__ float bf_lo(uint32 v) { return __uint_as_float(v << 16); }
__device__ __forceinline__ float bf_hi(uint32 v) { return __uint_as_float(v & 0xffff0000u); }

__device__ __forceinline__ short rne16(float v, float* back) {
    uint32 u = __float_as_uint(v);
    uint32 r = (u + 0x7fffu + ((u >> 16) & 1u)) >> 16;
    *back = __uint_as_float(r << 16);
    return (short)r;
}

// ---- prep: x -> xb (row-major packed bf16 hi) ; weights -> combined hi/lo ----
__global__ void k_prep(const float* __restrict__ x, uint32* __restrict__ xb, long n4,
                       const float* __restrict__ W1l, const float* __restrict__ W1r,
                       const float* __restrict__ W2l, const float* __restrict__ W2r,
                       short* __restrict__ W1cH, short* __restrict__ W1cL,
                       short* __restrict__ W2cH, short* __restrict__ W2cL) {
    long i = (long)blockIdx.x * blockDim.x + threadIdx.x;
    if (i < n4) {
        float4 v = ((const float4*)x)[i];
        float back;
        short h0 = rne16(v.x, &back);
        short h1 = rne16(v.y, &back);
        short h2 = rne16(v.z, &back);
        short h3 = rne16(v.w, &back);
        uint2 o;
        o.x = (uint32)(unsigned short)h0 | ((uint32)(unsigned short)h1 << 16);
        o.y = (uint32)(unsigned short)h2 | ((uint32)(unsigned short)h3 << 16);
        ((uint2*)xb)[i] = o;
        return;
    }
    int i2 = (int)(i - n4);
    float back;
    if (i2 < 32768) {
        int j = i2 >> 8, k = i2 & 255;
        float v = (k < 128) ? W1l[j * 128 + k] : W1r[j * 128 + k - 128];
        float hb;
        short hs = rne16(v, &hb);
        short ls = rne16(v - hb, &back);
        W1cH[i2] = hs;
        W1cL[i2] = ls;
    } else if (i2 < 32768 + 16384) {
        int i3 = i2 - 32768;
        int j = i3 >> 7, k = i3 & 127;
        float v = (j < 64) ? W2l[j * 128 + k] : W2r[(j - 64) * 128 + k];
        float hb;
        short hs = rne16(v, &hb);
        short ls = rne16(v - hb, &back);
        W2cH[i3] = hs;
        W2cL[i3] = ls;
    }
}

// ---- bucketed CSR build (unchanged) ----

__global__ void k_bcount(const int* __restrict__ ei, int E, int NB,
                         int* __restrict__ bucket_cnt) {
    __shared__ int hist[1024];
    int t = threadIdx.x;
    for (int i = t; i < NB; i += 256) hist[i] = 0;
    __syncthreads();
    int stride = gridDim.x * 256;
    for (int e = blockIdx.x * 256 + t; e < E; e += stride)
        atomicAdd(&hist[ei[E + e] >> 8], 1);
    __syncthreads();
    for (int i = t; i < NB; i += 256) {
        int c = hist[i];
        if (c) atomicAdd(&bucket_cnt[i], c);
    }
}

__global__ void k_bscan(const int* __restrict__ bucket_cnt, int NB, int E,
                        int* __restrict__ bucket_off, int* __restrict__ bucket_cur) {
    __shared__ int s[1024];
    int t = threadIdx.x;
    int v = (t < NB) ? bucket_cnt[t] : 0;
    s[t] = v;
    __syncthreads();
    for (int o = 1; o < 1024; o <<= 1) {
        int u = (t >= o) ? s[t - o] : 0;
        __syncthreads();
        s[t] += u;
        __syncthreads();
    }
    int ex = s[t] - v;
    if (t < NB) { bucket_off[t] = ex; bucket_cur[t] = ex; }
    if (t == NB - 1) bucket_off[NB] = ex + v;
}

__global__ void k_bscatter(const int* __restrict__ ei, int E, int NB,
                           int* __restrict__ bucket_cur, uint32* __restrict__ eb) {
    __shared__ int hist[1024];
    __shared__ int base[1024];
    int t = threadIdx.x;
    for (int i = t; i < NB; i += 256) hist[i] = 0;
    __syncthreads();
    int stride = gridDim.x * 256;
    for (int e = blockIdx.x * 256 + t; e < E; e += stride)
        atomicAdd(&hist[ei[E + e] >> 8], 1);
    __syncthreads();
    for (int i = t; i < NB; i += 256) {
        int c = hist[i];
        base[i] = c ? atomicAdd(&bucket_cur[i], c) : 0;
        hist[i] = 0;
    }
    __syncthreads();
    for (int e = blockIdx.x * 256 + t; e < E; e += stride) {
        int d = ei[E + e];
        int b = d >> 8;
        int r = atomicAdd(&hist[b], 1);
        eb[base[b] + r] = ((uint32)(d & 255) << 24) | (uint32)ei[e];
    }
}

__global__ void k_bfinal(const uint32* __restrict__ eb,
                         const int* __restrict__ bucket_off,
                         int* __restrict__ row_ptr, int* __restrict__ col,
                         int N, int E) {
    __shared__ int deg[256];
    __shared__ int sc[256];
    __shared__ int cur[256];
    int b = blockIdx.x;
    int t = threadIdx.x;
    int beg = bucket_off[b], end = bucket_off[b + 1];
    deg[t] = 0;
    __syncthreads();
    for (int e = beg + t; e < end; e += 256)
        atomicAdd(&deg[eb[e] >> 24], 1);
    __syncthreads();
    int v = deg[t];
    sc[t] = v;
    __syncthreads();
    for (int o = 1; o < 256; o <<= 1) {
        int u = (t >= o) ? sc[t - o] : 0;
        __syncthreads();
        sc[t] += u;
        __syncthreads();
    }
    int ex = sc[t] - v;
    int node = b * 256 + t;
    if (node < N) row_ptr[node] = beg + ex;
    if (b == gridDim.x - 1 && t == 0) row_ptr[N] = E;
    cur[t] = ex;
    __syncthreads();
    for (int e = beg + t; e < end; e += 256) {
        uint32 u = eb[e];
        int r = atomicAdd(&cur[u >> 24], 1);
        col[beg + r] = (int)(u & 0xFFFFFFu);
    }
}

// ---- aggregation 1: wave/node, subgroup g (of 4) owns consecutive edges,
// vector col loads, raw-hi accumulate; emits row-major mh/ml bf16 ----

__global__ void k_agg_mean(const int* __restrict__ rp, const int* __restrict__ col,
                           const uint32* __restrict__ xb,
                           short* __restrict__ mh, short* __restrict__ ml, int N) {
    int node = blockIdx.x * 4 + (threadIdx.x >> 6);
    if (node >= N) return;
    node = __builtin_amdgcn_readfirstlane(node);
    int lane = threadIdx.x & 63;
    int g = lane >> 4;
    int f = lane & 15;
    int beg = rp[node], end = rp[node + 1];
    const uint4* xb4 = (const uint4*)xb;  // row = 16 uint4
    float s[8];
#pragma unroll
    for (int j = 0; j < 8; j++) s[j] = 0.f;

#define ACC_RAW(v)                                                      \
    { s[0] += bf_lo(v.x); s[1] += __uint_as_float(v.x);                 \
      s[2] += bf_lo(v.y); s[3] += __uint_as_float(v.y);                 \
      s[4] += bf_lo(v.z); s[5] += __uint_as_float(v.z);                 \
      s[6] += bf_lo(v.w); s[7] += __uint_as_float(v.w); }

    int e = beg;
    for (; e + 16 <= end; e += 16) {
        uint4 cv = *(const uint4*)(col + e + 4 * g);  // subgroup's 4 edges
        uint4 v0 = xb4[(size_t)cv.x * 16 + f];
        uint4 v1 = xb4[(size_t)cv.y * 16 + f];
        uint4 v2 = xb4[(size_t)cv.z * 16 + f];
        uint4 v3 = xb4[(size_t)cv.w * 16 + f];
        ACC_RAW(v0); ACC_RAW(v1); ACC_RAW(v2); ACC_RAW(v3);
    }
    for (; e + 8 <= end; e += 8) {
        uint2 cv = *(const uint2*)(col + e + 2 * g);
        uint4 v0 = xb4[(size_t)cv.x * 16 + f];
        uint4 v1 = xb4[(size_t)cv.y * 16 + f];
        ACC_RAW(v0); ACC_RAW(v1);
    }
    int rem = end - e;
    if (2 * g < rem) {
        uint4 v0 = xb4[(size_t)col[e + 2 * g] * 16 + f];
        ACC_RAW(v0);
    }
    if (2 * g + 1 < rem) {
        uint4 v0 = xb4[(size_t)col[e + 2 * g + 1] * 16 + f];
        ACC_RAW(v0);
    }
#undef ACC_RAW
#pragma unroll
    for (int j = 0; j < 8; j++) {
        s[j] += __shfl_xor(s[j], 16);
        s[j] += __shfl_xor(s[j], 32);
    }
    if (g == 0) {
        float inv = 1.0f / (float)max(end - beg, 1);
        uint32 H[4], L[4];
#pragma unroll
        for (int p = 0; p < 4; p++) {
            float m0 = s[2 * p] * inv, m1 = s[2 * p + 1] * inv;
            float b;
            short h0 = rne16(m0, &b);
            short l0 = rne16(m0 - b, &b);
            short h1 = rne16(m1, &b);
            short l1 = rne16(m1 - b, &b);
            H[p] = (uint32)(unsigned short)h0 | ((uint32)(unsigned short)h1 << 16);
            L[p] = (uint32)(unsigned short)l0 | ((uint32)(unsigned short)l1 << 16);
        }
        size_t idx = (size_t)node * 128 + f * 8;  // shorts
        *(uint4*)&mh[idx] = make_uint4(H[0], H[1], H[2], H[3]);
        *(uint4*)&ml[idx] = make_uint4(L[0], L[1], L[2], L[3]);
    }
}

// ---- fused transposed MFMA GEMMs: h^T = relu(W1.[mean|x]^T + b1) in LDS,
// then (hl|hr)^T = W2.h^T. A = weights (lane m = j), B = activations
// (lane m = node). C-layout: col = node, row = j. ----

#define HROW 132  // padded h row stride in shorts (264 B -> 2-way-free banks)

__global__ __launch_bounds__(256) void k_mgemm(
        const short* __restrict__ mh, const short* __restrict__ ml,
        const uint32* __restrict__ xb,
        const short* __restrict__ W1cH, const short* __restrict__ W1cL,
        const short* __restrict__ W2cH, const short* __restrict__ W2cL,
        const float* __restrict__ b1, const float* __restrict__ b2,
        unsigned short* __restrict__ hl, float* __restrict__ hr, int N) {
    __shared__ short hH[128 * HROW];
    __shared__ short hL[128 * HROW];
    int t = threadIdx.x;
    int w = t >> 6, lane = t & 63;
    int m = lane & 31, hh = lane >> 5;
    int node0 = blockIdx.x * 128;
    int mynode = node0 + 32 * w + m;           // B-lane node
    const short* xs = (const short*)xb;
    f32x16 acc[4];
#pragma unroll
    for (int i = 0; i < 4; i++)
#pragma unroll
        for (int r = 0; r < 16; r++) acc[i][r] = 0.f;

    // GEMM1 seg 0: mean (3-term), k = 0..127
    for (int kc = 0; kc < 8; kc++) {
        int ko = 16 * kc + 8 * hh;
        bf16x8 bH = *(const bf16x8*)(mh + (size_t)mynode * 128 + ko);
        bf16x8 bL = *(const bf16x8*)(ml + (size_t)mynode * 128 + ko);
#pragma unroll
        for (int jt = 0; jt < 4; jt++) {
            bf16x8 aH = *(const bf16x8*)(W1cH + (32 * jt + m) * 256 + ko);
            bf16x8 aL = *(const bf16x8*)(W1cL + (32 * jt + m) * 256 + ko);
            acc[jt] = __builtin_amdgcn_mfma_f32_32x32x16_bf16(aH, bH, acc[jt], 0, 0, 0);
            acc[jt] = __builtin_amdgcn_mfma_f32_32x32x16_bf16(aL, bH, acc[jt], 0, 0, 0);
            acc[jt] = __builtin_amdgcn_mfma_f32_32x32x16_bf16(aH, bL, acc[jt], 0, 0, 0);
        }
    }
    // GEMM1 seg 1: x (2-term), k = 128..255
    for (int kc = 0; kc < 8; kc++) {
        int ko = 16 * kc + 8 * hh;
        bf16x8 bH = *(const bf16x8*)(xs + (size_t)mynode * 128 + ko);
#pragma unroll
        for (int jt = 0; jt < 4; jt++) {
            bf16x8 aH = *(const bf16x8*)(W1cH + (32 * jt + m) * 256 + 128 + ko);
            bf16x8 aL = *(const bf16x8*)(W1cL + (32 * jt + m) * 256 + 128 + ko);
            acc[jt] = __builtin_amdgcn_mfma_f32_32x32x16_bf16(aH, bH, acc[jt], 0, 0, 0);
            acc[jt] = __builtin_amdgcn_mfma_f32_32x32x16_bf16(aL, bH, acc[jt], 0, 0, 0);
        }
    }
    // epilogue 1: relu + bias, split hi/lo -> LDS h[node_local][j]
    {
        int nl = 32 * w + m;  // node_local (C col = node)
#pragma unroll
        for (int jt = 0; jt < 4; jt++) {
#pragma unroll
            for (int rg = 0; rg < 4; rg++) {
                int j0 = 32 * jt + 8 * rg + 4 * hh;
                float4 bv = *(const float4*)(b1 + j0);
                float bb[4] = {bv.x, bv.y, bv.z, bv.w};
                bf16x4 h4, l4;
#pragma unroll
                for (int q = 0; q < 4; q++) {
                    float v = fmaxf(acc[jt][4 * rg + q] + bb[q], 0.f);
                    float back;
                    h4[q] = rne16(v, &back);
                    l4[q] = rne16(v - back, &back);
                }
                *(bf16x4*)&hH[nl * HROW + j0] = h4;
                *(bf16x4*)&hL[nl * HROW + j0] = l4;
            }
        }
    }
    __syncthreads();
    // GEMM2: (hl|hr)^T = W2 . h^T, K=128, 3-term
#pragma unroll
    for (int i = 0; i < 4; i++)
#pragma unroll
        for (int r = 0; r < 16; r++) acc[i][r] = 0.f;
    {
        int nl = 32 * w + m;
        for (int kc = 0; kc < 8; kc++) {
            int ko = 16 * kc + 8 * hh;
            bf16x8 bH = *(const bf16x8*)&hH[nl * HROW + ko];
            bf16x8 bL = *(const bf16x8*)&hL[nl * HROW + ko];
#pragma unroll
            for (int jt = 0; jt < 4; jt++) {
                bf16x8 aH = *(const bf16x8*)(W2cH + (32 * jt + m) * 128 + ko);
                bf16x8 aL = *(const bf16x8*)(W2cL + (32 * jt + m) * 128 + ko);
                acc[jt] = __builtin_amdgcn_mfma_f32_32x32x16_bf16(aH, bH, acc[jt], 0, 0, 0);
                acc[jt] = __builtin_amdgcn_mfma_f32_32x32x16_bf16(aL, bH, acc[jt], 0, 0, 0);
                acc[jt] = __builtin_amdgcn_mfma_f32_32x32x16_bf16(aH, bL, acc[jt], 0, 0, 0);
            }
        }
    }
    if (mynode >= N) return;
    // epilogue 2: jt 0,1 -> hl bf16 [node][64]; jt 2,3 -> hr fp32 [node][64] + b2
#pragma unroll
    for (int jt = 0; jt < 2; jt++) {
#pragma unroll
        for (int rg = 0; rg < 4; rg++) {
            int j0 = 32 * jt + 8 * rg + 4 * hh;
            uint2 o;
            o.x = pack_bf16_rne(acc[jt][4 * rg + 0], acc[jt][4 * rg + 1]);
            o.y = pack_bf16_rne(acc[jt][4 * rg + 2], acc[jt][4 * rg + 3]);
            *(uint2*)&hl[(size_t)mynode * 64 + j0] = o;
        }
    }
#pragma unroll
    for (int jt = 2; jt < 4; jt++) {
#pragma unroll
        for (int rg = 0; rg < 4; rg++) {
            int j0 = 32 * (jt - 2) + 8 * rg + 4 * hh;
            float4 bv = *(const float4*)(b2 + j0);
            float4 o;
            o.x = acc[jt][4 * rg + 0] + bv.x;
            o.y = acc[jt][4 * rg + 1] + bv.y;
            o.z = acc[jt][4 * rg + 2] + bv.z;
            o.w = acc[jt][4 * rg + 3] + bv.w;
            *(float4*)&hr[(size_t)mynode * 64 + j0] = o;
        }
    }
}

// ---- aggregation 2: wave/node, 8 subgroups of 8 lanes, masked unpack ----

__global__ void k_agg_out(const int* __restrict__ rp, const int* __restrict__ col,
                          const uint32* __restrict__ hl, const float* __restrict__ hr,
                          float* __restrict__ out, int N) {
    int node = blockIdx.x * 4 + (threadIdx.x >> 6);
    if (node >= N) return;
    node = __builtin_amdgcn_readfirstlane(node);
    int lane = threadIdx.x & 63;
    int g = lane >> 3;
    int f = lane & 7;
    int beg = rp[node], end = rp[node + 1];
    const uint4* hl4 = (const uint4*)hl;  // row = 8 uint4
    float s[8];
#pragma unroll
    for (int j = 0; j < 8; j++) s[j] = 0.f;

#define ACC_MSK(v)                                          \
    { s[0] += bf_lo(v.x); s[1] += bf_hi(v.x);               \
      s[2] += bf_lo(v.y); s[3] += bf_hi(v.y);               \
      s[4] += bf_lo(v.z); s[5] += bf_hi(v.z);               \
      s[6] += bf_lo(v.w); s[7] += bf_hi(v.w); }

    int e = beg;
    for (; e + 16 <= end; e += 16) {
        uint2 cv = *(const uint2*)(col + e + 2 * g);
        uint4 v0 = hl4[(size_t)cv.x * 8 + f];
        uint4 v1 = hl4[(size_t)cv.y * 8 + f];
        ACC_MSK(v0); ACC_MSK(v1);
    }
    for (; e + 8 <= end; e += 8) {
        uint4 v0 = hl4[(size_t)col[e + g] * 8 + f];
        ACC_MSK(v0);
    }
    int rem = end - e;
    if (g < rem) {
        uint4 v0 = hl4[(size_t)col[e + g] * 8 + f];
        ACC_MSK(v0);
    }
#undef ACC_MSK
#pragma unroll
    for (int j = 0; j < 8; j++) {
        s[j] += __shfl_xor(s[j], 8);
        s[j] += __shfl_xor(s[j], 16);
        s[j] += __shfl_xor(s[j], 32);
    }
    if (g == 0) {
        float inv = 1.0f / (float)max(end - beg, 1);
        const float* hrp = hr + (size_t)node * 64 + f * 8;
        float4 h0 = *(const float4*)(hrp);
        float4 h1 = *(const float4*)(hrp + 4);
        float4 o0, o1;
        o0.x = s[0] * inv + h0.x;
        o0.y = s[1] * inv + h0.y;
        o0.z = s[2] * inv + h0.z;
        o0.w = s[3] * inv + h0.w;
        o1.x = s[4] * inv + h1.x;
        o1.y = s[5] * inv + h1.y;
        o1.z = s[6] * inv + h1.z;
        o1.w = s[7] * inv + h1.w;
        float* op = out + (size_t)node * 64 + f * 8;
        *(float4*)(op) = o0;
        *(float4*)(op + 4) = o1;
    }
}

extern "C" void kernel_launch(void* const* d_in, const int* in_sizes, int n_in,
                              void* d_out, int out_size, void* d_ws, size_t ws_size,
                              hipStream_t stream) {
    const float* x   = (const float*)d_in[0];
    const float* W1l = (const float*)d_in[1];
    const float* W1r = (const float*)d_in[2];
    const float* b1  = (const float*)d_in[3];
    const float* W2l = (const float*)d_in[4];
    const float* W2r = (const float*)d_in[5];
    const float* b2  = (const float*)d_in[6];
    const int*   ei  = (const int*)d_in[7];
    int N = in_sizes[0] / 128;
    int E = in_sizes[7] / 2;
    int NB = (N + 255) >> 8;
    int gb = (N + 127) / 128;
    int Np = gb * 128;
    float* out = (float*)d_out;

    char* w = (char*)d_ws;
    size_t off = 0;
    auto alloc = [&](size_t bytes) -> char* {
        char* p = w + off;
        off += (bytes + 255) & ~(size_t)255;
        return p;
    };
    int*   row_ptr = (int*)alloc((size_t)(N + 1) * 4);
    int*   bcnt    = (int*)alloc((size_t)(NB + 1) * 4);
    int*   boff    = (int*)alloc((size_t)(NB + 1) * 4);
    int*   bcur    = (int*)alloc((size_t)(NB + 1) * 4);
    short* W1cH    = (short*)alloc(32768 * 2);
    short* W1cL    = (short*)alloc(32768 * 2);
    short* W2cH    = (short*)alloc(16384 * 2);
    short* W2cL    = (short*)alloc(16384 * 2);
    int*   col     = (int*)alloc((size_t)E * 4);
    uint32* xb     = (uint32*)alloc((size_t)Np * 64 * 4);      // 25.6 MB
    short* mh      = (short*)alloc((size_t)Np * 128 * 2);      // 25.6 MB
    short* ml      = (short*)alloc((size_t)Np * 128 * 2);      // 25.6 MB
    unsigned short* hl = (unsigned short*)alloc((size_t)N * 64 * 2);  // 12.8 MB
    float* hr      = (float*)alloc((size_t)N * 64 * 4);        // 25.6 MB
    uint32* eb     = (uint32*)hl;  // dead after k_bfinal; hl written by k_mgemm later

    hipMemsetAsync(bcnt, 0, (size_t)NB * 4, stream);
    long n4 = (long)N * 32;
    long prep_items = n4 + 32768 + 16384;
    k_prep<<<(int)((prep_items + 255) / 256), 256, 0, stream>>>(
        x, xb, n4, W1l, W1r, W2l, W2r, W1cH, W1cL, W2cH, W2cL);
    k_bcount<<<256, 256, 0, stream>>>(ei, E, NB, bcnt);
    k_bscan<<<1, 1024, 0, stream>>>(bcnt, NB, E, boff, bcur);
    k_bscatter<<<128, 256, 0, stream>>>(ei, E, NB, bcur, eb);
    k_bfinal<<<NB, 256, 0, stream>>>(eb, boff, row_ptr, col, N, E);

    int ab = (N + 3) / 4;
    k_agg_mean<<<ab, 256, 0, stream>>>(row_ptr, col, xb, mh, ml, N);
    k_mgemm<<<gb, 256, 0, stream>>>(mh, ml, xb, W1cH, W1cL, W2cH, W2cL,
                                    b1, b2, hl, hr, N);
    k_agg_out<<<ab, 256, 0, stream>>>(row_ptr, col, (const uint32*)hl, hr, out, N);
}